// Round 4
// baseline (4759.307 us; speedup 1.0000x reference)
//
#include <hip/hip_runtime.h>
#include <hip/hip_bf16.h>

typedef __hip_bfloat16 bf16;

#define INV_SQRT_2 0.70710678118654752440f
#define INV_SQRT_3 0.57735026918962576451f

__device__ __forceinline__ float toF(float x) { return x; }
__device__ __forceinline__ float toF(bf16 x) { return __bfloat162float(x); }
__device__ __forceinline__ float siluf(float x) { return x / (1.f + __expf(-x)); }
__device__ __forceinline__ bf16 toB(float x) { return __float2bfloat16(x); }

template <typename T> __device__ __forceinline__ T fromF(float x);
template <> __device__ __forceinline__ float fromF<float>(float x) { return x; }
template <> __device__ __forceinline__ bf16 fromF<bf16>(float x) { return __float2bfloat16(x); }

// ---- dtype detector: probe rbf_h (uniform [0,1]) interpreted as bf16 words.
// bf16-true data: all values in [0,1] -> bad==0 -> flag=0.
// f32-true data: even words are f32-mantissa garbage -> many bad -> flag=1.
__global__ void k_detect(const unsigned short* __restrict__ probe, int* __restrict__ flag) {
  __shared__ int cnt;
  if (threadIdx.x == 0) cnt = 0;
  __syncthreads();
  int bad = 0;
  for (int i = threadIdx.x; i < 256; i += 64) {
    unsigned int u = (unsigned int)probe[i] << 16;
    float v = __uint_as_float(u);
    if (!(v == v) || fabsf(v) > 4.f || v < -0.25f) bad++;
  }
  atomicAdd(&cnt, bad);
  __syncthreads();
  if (threadIdx.x == 0) *flag = (cnt > 16) ? 1 : 0;
}

__global__ void k_zero(float* __restrict__ p, int n) {
  int i = blockIdx.x * blockDim.x + threadIdx.x;
  if (i < n) p[i] = 0.f;
}

#define GUARD if (*flag != want) return;

// ---------------- generic GEMM: out(bf16) = act(A @ W) ----------------
template <typename TA, typename TW, int ACT>
__global__ void k_gemm_b(const int* __restrict__ flag, int want,
                         const TA* __restrict__ A, const TW* __restrict__ W,
                         bf16* __restrict__ out, int M, int K, int Nc) {
  GUARD
  int idx = blockIdx.x * blockDim.x + threadIdx.x;
  if (idx >= M * Nc) return;
  int c = idx % Nc;
  int r = idx / Nc;
  const TA* a = A + (size_t)r * K;
  float acc = 0.f;
#pragma unroll 8
  for (int k = 0; k < K; ++k) acc += toF(a[k]) * toF(W[k * Nc + c]);
  out[idx] = toB(ACT ? siluf(acc) : acc);
}

// ---- m_kt pre: out = silu(m_st @ Wt_mkt) * (rbf3 @ Wt_rbf) ----
template <typename TIN>
__global__ void k_mkt_b(const int* __restrict__ flag, int want,
                        const TIN* __restrict__ mst, const TIN* __restrict__ rbf3,
                        const TIN* __restrict__ Wmkt, const TIN* __restrict__ Wrbf,
                        bf16* __restrict__ out, int E) {
  GUARD
  int idx = blockIdx.x * blockDim.x + threadIdx.x;
  if (idx >= E * 128) return;
  int c = idx & 127;
  int e = idx >> 7;
  float acc = 0.f;
#pragma unroll 8
  for (int k = 0; k < 128; ++k) acc += toF(mst[(size_t)e * 128 + k]) * toF(Wmkt[k * 128 + c]);
  float g = 0.f;
#pragma unroll
  for (int k = 0; k < 16; ++k) g += toF(rbf3[(size_t)e * 16 + k]) * toF(Wrbf[k * 128 + c]);
  out[idx] = toB(siluf(acc) * g);
}

// ---- efficient bilinear: one edge per block (64 threads) ----
template <typename TIN>
__global__ void k_bilinear_b(const int* __restrict__ flag, int want,
                             const TIN* __restrict__ basis, const bf16* __restrict__ msrc,
                             const int* __restrict__ gidx, const TIN* __restrict__ W,
                             bf16* __restrict__ out) {
  GUARD
  int e = blockIdx.x;
  int tid = threadIdx.x;  // 0..63
  __shared__ float sumk[16 * 64];
#pragma unroll
  for (int b = 0; b < 16; ++b) sumk[b * 64 + tid] = 0.f;
  __syncthreads();
  for (int k = 0; k < 6; ++k) {
    int t = e * 6 + k;
    int row = gidx[t];
    float mi = toF(msrc[(size_t)row * 64 + tid]);
    const TIN* bs = basis + (size_t)t * 16;
#pragma unroll
    for (int b = 0; b < 16; ++b) sumk[b * 64 + tid] += toF(bs[b]) * mi;
  }
  __syncthreads();
  float acc = 0.f;
  for (int i = 0; i < 64; ++i) {
#pragma unroll
    for (int b = 0; b < 16; ++b) acc += sumk[b * 64 + i] * toF(W[i * 1024 + b * 64 + tid]);
  }
  out[(size_t)e * 64 + tid] = toB(acc);
}

// ---- combine: x = (x_skip + x3 + x4) * inv_sqrt3 ----
template <typename TIN>
__global__ void k_combine_b(const int* __restrict__ flag, int want,
                            const TIN* __restrict__ mst, const TIN* __restrict__ Wskip,
                            const bf16* __restrict__ xt, const TIN* __restrict__ Wt_st,
                            const TIN* __restrict__ Wt_ts, const bf16* __restrict__ xq,
                            const TIN* __restrict__ Wq_st, const TIN* __restrict__ Wq_ts,
                            const int* __restrict__ idx_swap, bf16* __restrict__ xout, int E) {
  GUARD
  int idx = blockIdx.x * blockDim.x + threadIdx.x;
  if (idx >= E * 128) return;
  int c = idx & 127;
  int e = idx >> 7;
  int s = idx_swap[e];
  float v = 0.f;
#pragma unroll 8
  for (int k = 0; k < 128; ++k) v += toF(mst[(size_t)e * 128 + k]) * toF(Wskip[k * 128 + c]);
  float a3 = 0.f, b3 = 0.f, a4 = 0.f, b4 = 0.f;
#pragma unroll 8
  for (int k = 0; k < 64; ++k) {
    a3 += toF(xt[(size_t)e * 64 + k]) * toF(Wt_st[k * 128 + c]);
    b3 += toF(xt[(size_t)s * 64 + k]) * toF(Wt_ts[k * 128 + c]);
    a4 += toF(xq[(size_t)e * 64 + k]) * toF(Wq_st[k * 128 + c]);
    b4 += toF(xq[(size_t)s * 64 + k]) * toF(Wq_ts[k * 128 + c]);
  }
  float x3 = (siluf(a3) + siluf(b3)) * INV_SQRT_2;
  float x4 = (siluf(a4) + siluf(b4)) * INV_SQRT_2;
  xout[idx] = toB((v + x3 + x4) * INV_SQRT_3);
}

// ---- fused residual layer: v = (x + silu(silu(x@W0)@W1)) * r2 ----
// MODE 0: X <- v.  MODE 1/2: outp <- (extra + v)*r2.
template <int MODE, typename TIN, typename TEX, typename TOUT>
__global__ void k_resfused(const int* __restrict__ flag, int want,
                           bf16* __restrict__ X, const TIN* __restrict__ W0,
                           const TIN* __restrict__ W1, const TEX* __restrict__ extra,
                           TOUT* __restrict__ outp, int M) {
  GUARD
  int lr = threadIdx.x >> 7;
  int c = threadIdx.x & 127;
  int row = blockIdx.x * 2 + lr;
  __shared__ float xs[2][128];
  __shared__ float ys[2][128];
  size_t off = (size_t)row * 128 + c;
  xs[lr][c] = toF(X[off]);
  __syncthreads();
  float acc = 0.f;
#pragma unroll 8
  for (int k = 0; k < 128; ++k) acc += xs[lr][k] * toF(W0[k * 128 + c]);
  ys[lr][c] = siluf(acc);
  __syncthreads();
  float acc2 = 0.f;
#pragma unroll 8
  for (int k = 0; k < 128; ++k) acc2 += ys[lr][k] * toF(W1[k * 128 + c]);
  float v = (xs[lr][c] + siluf(acc2)) * INV_SQRT_2;
  if (MODE == 0) {
    X[off] = toB(v);
  } else {
    outp[off] = fromF<TOUT>((toF(extra[off]) + v) * INV_SQRT_2);
  }
}

// ---- atom embedding scatter ----
template <typename TIN>
__global__ void k_scatter(const int* __restrict__ flag, int want,
                          const bf16* __restrict__ m, const TIN* __restrict__ rbf_h,
                          const TIN* __restrict__ Wrbf, const int* __restrict__ idx_t,
                          float* __restrict__ h2) {
  GUARD
  int e = blockIdx.x;
  int c = threadIdx.x;
  float g = 0.f;
#pragma unroll
  for (int k = 0; k < 16; ++k) g += toF(rbf_h[(size_t)e * 16 + k]) * toF(Wrbf[k * 128 + c]);
  float val = toF(m[(size_t)e * 128 + c]) * g;
  atomicAdd(&h2[(size_t)idx_t[e] * 128 + c], val);
}

// ---- h_new = (h + X)*r2 -> out (TOUT) and X (bf16, for ASI) ----
template <typename TIN, typename TOUT>
__global__ void k_hnew_b(const int* __restrict__ flag, int want,
                         const TIN* __restrict__ h, bf16* __restrict__ X,
                         TOUT* __restrict__ out, int n) {
  GUARD
  int idx = blockIdx.x * blockDim.x + threadIdx.x;
  if (idx >= n) return;
  float v = (toF(h[idx]) + toF(X[idx])) * INV_SQRT_2;
  X[idx] = toB(v);
  out[idx] = fromF<TOUT>(v);
}

// ---- ASI: m2 = silu(concat[h_new[s], h_new[t], m] @ W_asi) ----
template <typename TIN>
__global__ void k_asi_b(const int* __restrict__ flag, int want,
                        const bf16* __restrict__ hnew, const bf16* __restrict__ m,
                        const int* __restrict__ idx_s, const int* __restrict__ idx_t,
                        const TIN* __restrict__ W, bf16* __restrict__ out, int E) {
  GUARD
  int idx = blockIdx.x * blockDim.x + threadIdx.x;
  if (idx >= E * 128) return;
  int c = idx & 127;
  int e = idx >> 7;
  int s = idx_s[e];
  int t = idx_t[e];
  float acc = 0.f;
#pragma unroll 8
  for (int k = 0; k < 128; ++k) acc += toF(hnew[(size_t)s * 128 + k]) * toF(W[k * 128 + c]);
#pragma unroll 8
  for (int k = 0; k < 128; ++k) acc += toF(hnew[(size_t)t * 128 + k]) * toF(W[(128 + k) * 128 + c]);
#pragma unroll 8
  for (int k = 0; k < 128; ++k) acc += toF(m[(size_t)e * 128 + k]) * toF(W[(256 + k) * 128 + c]);
  out[idx] = toB(siluf(acc));
}

template <typename TIN, typename TOUT>
static void run_pipeline(void* const* d_in, int N, int E, void* d_out,
                         bf16* R1, bf16* R2, float* h2, bf16* Rn2,
                         const int* flag, int want, hipStream_t stream) {
  const TIN* h      = (const TIN*)d_in[0];
  const TIN* m_st   = (const TIN*)d_in[1];
  const TIN* rbf_h  = (const TIN*)d_in[2];
  const TIN* rbf3   = (const TIN*)d_in[3];
  const TIN* cbf3   = (const TIN*)d_in[4];
  const TIN* sbf4   = (const TIN*)d_in[5];
  const int* idx_s   = (const int*)d_in[6];
  const int* idx_t   = (const int*)d_in[7];
  const int* idx_sw  = (const int*)d_in[8];
  const int* id3_kt  = (const int*)d_in[9];
  const int* enb_idx = (const int*)d_in[12];
  const TIN* W_skip   = (const TIN*)d_in[16];
  const TIN* Wt_mkt   = (const TIN*)d_in[17];
  const TIN* Wt_rbf   = (const TIN*)d_in[18];
  const TIN* Wt_down  = (const TIN*)d_in[19];
  const TIN* Wt_cbf   = (const TIN*)d_in[20];
  const TIN* Wt_up_st = (const TIN*)d_in[21];
  const TIN* Wt_up_ts = (const TIN*)d_in[22];
  const TIN* Wq_down  = (const TIN*)d_in[23];
  const TIN* Wq_sbf   = (const TIN*)d_in[24];
  const TIN* Wq_up_st = (const TIN*)d_in[25];
  const TIN* Wq_up_ts = (const TIN*)d_in[26];
  const TIN* Wres_before = (const TIN*)d_in[27];
  const TIN* Wres_after  = (const TIN*)d_in[28];
  const TIN* Wres_m      = (const TIN*)d_in[29];
  const TIN* W_ae_rbf    = (const TIN*)d_in[30];
  const TIN* W_ae_dense  = (const TIN*)d_in[31];
  const TIN* W_ae_res    = (const TIN*)d_in[32];
  const TIN* W_asi       = (const TIN*)d_in[33];

  TOUT* out_h = (TOUT*)d_out;
  TOUT* out_m = out_h + (size_t)N * 128;

  bf16* m_d  = R1;
  bf16* m_kt = R1 + (size_t)E * 64;
  bf16* xq   = R2;
  bf16* xt   = R2 + (size_t)E * 64;

  const int W1o = 128 * 128;
  const int BS = 256;
  int gE128 = (E * 128 + BS - 1) / BS;
  int gE64  = (E * 64 + BS - 1) / BS;
  int gN128 = (N * 128 + BS - 1) / BS;

  k_gemm_b<TIN, TIN, 1><<<gE64, BS, 0, stream>>>(flag, want, m_st, Wq_down, m_d, E, 128, 64);
  k_mkt_b<TIN><<<gE128, BS, 0, stream>>>(flag, want, m_st, rbf3, Wt_mkt, Wt_rbf, R2, E);
  k_gemm_b<bf16, TIN, 1><<<gE64, BS, 0, stream>>>(flag, want, R2, Wt_down, m_kt, E, 128, 64);
  k_bilinear_b<TIN><<<E, 64, 0, stream>>>(flag, want, sbf4, m_d, enb_idx, Wq_sbf, xq);
  k_bilinear_b<TIN><<<E, 64, 0, stream>>>(flag, want, cbf3, m_kt, id3_kt, Wt_cbf, xt);
  k_combine_b<TIN><<<gE128, BS, 0, stream>>>(flag, want, m_st, W_skip, xt, Wt_up_st, Wt_up_ts,
                                             xq, Wq_up_st, Wq_up_ts, idx_sw, R1, E);
  k_resfused<1, TIN, TIN, bf16><<<E / 2, BS, 0, stream>>>(flag, want, R1, Wres_before,
                                                          Wres_before + W1o, m_st, R2, E);
  k_resfused<0, TIN, bf16, bf16><<<E / 2, BS, 0, stream>>>(flag, want, R2, Wres_after,
                                                           Wres_after + W1o, (const bf16*)nullptr,
                                                           (bf16*)nullptr, E);
  k_resfused<0, TIN, bf16, bf16><<<E / 2, BS, 0, stream>>>(flag, want, R2, Wres_after + 2 * W1o,
                                                           Wres_after + 3 * W1o, (const bf16*)nullptr,
                                                           (bf16*)nullptr, E);
  k_scatter<TIN><<<E, 128, 0, stream>>>(flag, want, R2, rbf_h, W_ae_rbf, idx_t, h2);
  k_gemm_b<float, TIN, 1><<<gN128, BS, 0, stream>>>(flag, want, h2, W_ae_dense, Rn2, N, 128, 128);
  k_resfused<0, TIN, bf16, bf16><<<N / 2, BS, 0, stream>>>(flag, want, Rn2, W_ae_res,
                                                           W_ae_res + W1o, (const bf16*)nullptr,
                                                           (bf16*)nullptr, N);
  k_resfused<0, TIN, bf16, bf16><<<N / 2, BS, 0, stream>>>(flag, want, Rn2, W_ae_res + 2 * W1o,
                                                           W_ae_res + 3 * W1o, (const bf16*)nullptr,
                                                           (bf16*)nullptr, N);
  k_hnew_b<TIN, TOUT><<<gN128, BS, 0, stream>>>(flag, want, h, Rn2, out_h, N * 128);
  k_asi_b<TIN><<<gE128, BS, 0, stream>>>(flag, want, Rn2, R2, idx_s, idx_t, W_asi, R1, E);
  k_resfused<2, TIN, bf16, TOUT><<<E / 2, BS, 0, stream>>>(flag, want, R1, Wres_m,
                                                           Wres_m + W1o, R2, out_m, E);
}

extern "C" void kernel_launch(void* const* d_in, const int* in_sizes, int n_in,
                              void* d_out, int out_size, void* d_ws, size_t ws_size,
                              hipStream_t stream) {
  const int D = 128;
  const int N = in_sizes[0] / D;   // 8000
  const int E = in_sizes[1] / D;   // 80000

  // workspace: 47.1 MB + flag
  bf16* R1  = (bf16*)d_ws;                      // E*128 bf16
  bf16* R2  = R1 + (size_t)E * 128;             // E*128 bf16
  float* h2 = (float*)(R2 + (size_t)E * 128);   // N*128 f32
  bf16* Rn2 = (bf16*)(h2 + (size_t)N * 128);    // N*128 bf16
  int* flag = (int*)(Rn2 + (size_t)N * 128);

  const int BS = 256;
  int gN128 = (N * 128 + BS - 1) / BS;

  // detect input dtype from rbf_h
  k_detect<<<1, 64, 0, stream>>>((const unsigned short*)d_in[2], flag);
  // zero the scatter accumulator (shared by both pipelines; only one runs scatter)
  k_zero<<<gN128, BS, 0, stream>>>(h2, N * 128);

  run_pipeline<bf16, bf16>(d_in, N, E, d_out, R1, R2, h2, Rn2, flag, 0, stream);
  run_pipeline<float, float>(d_in, N, E, d_out, R1, R2, h2, Rn2, flag, 1, stream);
}